// Round 1
// baseline (306.895 us; speedup 1.0000x reference)
//
#include <hip/hip_runtime.h>

#define NBATCH 2
#define NHEAD  16
#define NSEQ   2048
#define NDIM   64
#define NNX    1024
#define NBH    (NBATCH*NHEAD)
#define CEXPF  0.18033688011112042f   // log2(e)/sqrt(64)

typedef short          short8  __attribute__((ext_vector_type(8)));
typedef short          short4v __attribute__((ext_vector_type(4)));
typedef unsigned short us4     __attribute__((ext_vector_type(4)));
typedef unsigned short us8     __attribute__((ext_vector_type(8)));
typedef float          f32x4   __attribute__((ext_vector_type(4)));

__device__ __forceinline__ unsigned short f2bf(float f) {
    unsigned int u = __builtin_bit_cast(unsigned int, f);
    u += 0x7FFFu + ((u >> 16) & 1u);           // round-to-nearest-even
    return (unsigned short)(u >> 16);
}

__device__ __forceinline__ float fexp2(float x) {
#if __has_builtin(__builtin_amdgcn_exp2f)
    return __builtin_amdgcn_exp2f(x);
#else
    return exp2f(x);
#endif
}

__device__ __forceinline__ f32x4 mfma16(short8 a, short8 b, f32x4 c) {
    return __builtin_amdgcn_mfma_f32_16x16x32_bf16(a, b, c, 0, 0, 0);
}

// ---- prep: Qb = bf16 split-heads query [bh][s][d]; KKb = bf16 (key+key_r) ----
__global__ __launch_bounds__(256) void prep_qk(
        const float* __restrict__ q, const float* __restrict__ k,
        const float* __restrict__ kr,
        unsigned short* __restrict__ Qb, unsigned short* __restrict__ KKb) {
    const long i    = (long)blockIdx.x * 256 + threadIdx.x;   // 0..1048575
    const long flat = i << 2;
    const int dnx = (int)(flat & (NNX - 1));
    const int s   = (int)((flat >> 10) & (NSEQ - 1));
    const int b   = (int)(flat >> 21);
    const int h   = dnx >> 6;
    const int d   = dnx & 63;
    const long o  = ((long)(b*NHEAD + h) * NSEQ + s) * NDIM + d;
    const float4 qv = *(const float4*)(q  + flat);
    const float4 kv = *(const float4*)(k  + flat);
    const float4 rv = *(const float4*)(kr + flat);
    us4 qo, ko;
    qo[0]=f2bf(qv.x); qo[1]=f2bf(qv.y); qo[2]=f2bf(qv.z); qo[3]=f2bf(qv.w);
    ko[0]=f2bf(kv.x+rv.x); ko[1]=f2bf(kv.y+rv.y); ko[2]=f2bf(kv.z+rv.z); ko[3]=f2bf(kv.w+rv.w);
    *(us4*)(Qb  + o) = qo;
    *(us4*)(KKb + o) = ko;
}

// ---- prep: VT = bf16 value transposed per head: [bh][d][s] ----
__global__ __launch_bounds__(256) void prep_vt(const float* __restrict__ v,
        unsigned short* __restrict__ VT) {
    __shared__ unsigned short lds[64][66];
    const int bh = blockIdx.x & (NBH - 1);
    const int st = blockIdx.x >> 5;          // s-tile of 64
    const int b = bh >> 4, h = bh & 15;
    const int t  = threadIdx.x;
    const int sl = t >> 2;
    const int d0 = (t & 3) << 4;
    const float* src = v + ((long)b*NSEQ + st*64 + sl) * NNX + h*64 + d0;
    #pragma unroll
    for (int j = 0; j < 4; ++j) {
        float4 x = *(const float4*)(src + j*4);
        lds[d0 + j*4 + 0][sl] = f2bf(x.x);
        lds[d0 + j*4 + 1][sl] = f2bf(x.y);
        lds[d0 + j*4 + 2][sl] = f2bf(x.z);
        lds[d0 + j*4 + 3][sl] = f2bf(x.w);
    }
    __syncthreads();
    const int d  = t >> 2;
    const int s0 = (t & 3) << 4;
    unsigned short* dst = VT + ((long)bh*NDIM + d)*NSEQ + st*64 + s0;
    us8 o0, o1;
    #pragma unroll
    for (int j = 0; j < 8; ++j) { o0[j] = lds[d][s0+j]; o1[j] = lds[d][s0+8+j]; }
    *(us8*)(dst)     = o0;
    *(us8*)(dst + 8) = o1;
}

// ---- fused attention: per wave, two 16-row q-tiles (qA and 127-qA) ----
__global__ __launch_bounds__(256) void attn_main(
        const unsigned short* __restrict__ Qb,
        const unsigned short* __restrict__ KKb,
        const unsigned short* __restrict__ VT,
        float* __restrict__ outA, float* __restrict__ outAtt) {
    const int lane = threadIdx.x & 63;
    const int wid  = (blockIdx.x << 2) | (threadIdx.x >> 6);   // 0..2047
    const int bh = wid & (NBH - 1);
    const int qA = wid >> 5;            // 0..63
    const int qB = 127 - qA;            // 64..127  (balanced pairing)
    const int b = bh >> 4, h = bh & 15;
    const int r16 = lane & 15;
    const int g   = lane >> 4;
    const int q0A = qA << 4, q0B = qB << 4;
    const int nA = qA + 1, nB = qB + 1;          // causal tile counts
    const int qaA = q0A + r16, qaB = q0B + r16;

    const unsigned short* Qp = Qb  + (long)bh * (NSEQ*NDIM);
    const unsigned short* Kp = KKb + (long)bh * (NSEQ*NDIM);
    const unsigned short* Vp = VT  + (long)bh * (NDIM*NSEQ);

    const short8 qfA0 = *(const short8*)(Qp + (q0A + r16)*NDIM + g*8);
    const short8 qfA1 = *(const short8*)(Qp + (q0A + r16)*NDIM + g*8 + 32);
    const short8 qfB0 = *(const short8*)(Qp + (q0B + r16)*NDIM + g*8);
    const short8 qfB1 = *(const short8*)(Qp + (q0B + r16)*NDIM + g*8 + 32);

    const unsigned short* kptr = Kp + r16*NDIM + g*8;

    // ---------------- pass 1: row sums of exp (max-free; w bounded ~10) ----------------
    float lsA[4] = {0.f,0.f,0.f,0.f}, lsB[4] = {0.f,0.f,0.f,0.f};
    short8 c0 = *(const short8*)(kptr);
    short8 c1 = *(const short8*)(kptr + 32);
    for (int kt = 0; kt < nA; ++kt) {
        const short8 a0 = c0, a1 = c1;
        if (kt + 1 < nB) {
            const unsigned short* np = kptr + (kt + 1) * (16*NDIM);
            c0 = *(const short8*)(np);
            c1 = *(const short8*)(np + 32);
        }
        f32x4 sA = {0.f,0.f,0.f,0.f}, sB = {0.f,0.f,0.f,0.f};
        sA = mfma16(a0, qfA0, sA); sA = mfma16(a1, qfA1, sA);
        sB = mfma16(a0, qfB0, sB); sB = mfma16(a1, qfB1, sB);
        const int kb = (kt << 4) + (g << 2);
        #pragma unroll
        for (int r = 0; r < 4; ++r) {
            const float eA = fexp2(sA[r] * CEXPF);
            lsA[r] += (kb + r <= qaA) ? eA : 0.0f;
            lsB[r] += fexp2(sB[r] * CEXPF);     // k-range < q0B here: never masked
        }
    }
    for (int kt = nA; kt < nB; ++kt) {
        const short8 a0 = c0, a1 = c1;
        if (kt + 1 < nB) {
            const unsigned short* np = kptr + (kt + 1) * (16*NDIM);
            c0 = *(const short8*)(np);
            c1 = *(const short8*)(np + 32);
        }
        f32x4 sB = {0.f,0.f,0.f,0.f};
        sB = mfma16(a0, qfB0, sB); sB = mfma16(a1, qfB1, sB);
        const int kb = (kt << 4) + (g << 2);
        #pragma unroll
        for (int r = 0; r < 4; ++r) {
            const float eB = fexp2(sB[r] * CEXPF);
            lsB[r] += (kb + r <= qaB) ? eB : 0.0f;
        }
    }
    float lA = lsA[0]+lsA[1]+lsA[2]+lsA[3];
    float lB = lsB[0]+lsB[1]+lsB[2]+lsB[3];
    lA += __shfl_xor(lA, 16, 64); lA += __shfl_xor(lA, 32, 64);
    lB += __shfl_xor(lB, 16, 64); lB += __shfl_xor(lB, 32, 64);
    const float invA = 1.0f / lA;
    const float invB = 1.0f / lB;

    // ---------------- pass 2: recompute, write att (NT), accumulate PV ----------------
    const f32x4 zero4 = {0.f,0.f,0.f,0.f};
    f32x4 oaA[4], oaB[4];
    #pragma unroll
    for (int dt = 0; dt < 4; ++dt) { oaA[dt] = zero4; oaB[dt] = zero4; }

    float* attA = outAtt + ((long)bh*NSEQ + qaA) * NSEQ + (g << 2);
    float* attB = outAtt + ((long)bh*NSEQ + qaB) * NSEQ + (g << 2);
    const unsigned short* vbase = Vp + r16*NSEQ + (g << 2);

    c0 = *(const short8*)(kptr);
    c1 = *(const short8*)(kptr + 32);
    short4v vc[4];
    #pragma unroll
    for (int dt = 0; dt < 4; ++dt) vc[dt] = *(const short4v*)(vbase + dt*(16*NSEQ));

    for (int kt = 0; kt < nA; ++kt) {
        const short8 a0 = c0, a1 = c1;
        short4v vv[4];
        #pragma unroll
        for (int dt = 0; dt < 4; ++dt) vv[dt] = vc[dt];
        if (kt + 1 < nB) {
            const unsigned short* np = kptr + (kt + 1) * (16*NDIM);
            c0 = *(const short8*)(np);
            c1 = *(const short8*)(np + 32);
            const unsigned short* vp = vbase + (kt + 1) * 16;
            #pragma unroll
            for (int dt = 0; dt < 4; ++dt) vc[dt] = *(const short4v*)(vp + dt*(16*NSEQ));
        }
        f32x4 sA = {0.f,0.f,0.f,0.f}, sB = {0.f,0.f,0.f,0.f};
        sA = mfma16(a0, qfA0, sA); sA = mfma16(a1, qfA1, sA);
        sB = mfma16(a0, qfB0, sB); sB = mfma16(a1, qfB1, sB);
        const int kb = (kt << 4) + (g << 2);
        f32x4 pA, pB;
        #pragma unroll
        for (int r = 0; r < 4; ++r) {
            const float eA = fexp2(sA[r] * CEXPF) * invA;
            pA[r] = (kb + r <= qaA) ? eA : 0.0f;
            pB[r] = fexp2(sB[r] * CEXPF) * invB;
        }
        __builtin_nontemporal_store(pA, (f32x4*)(attA + (kt << 4)));
        __builtin_nontemporal_store(pB, (f32x4*)(attB + (kt << 4)));
        short8 bfA, bfB;
        #pragma unroll
        for (int r = 0; r < 4; ++r) {
            bfA[r] = (short)f2bf(pA[r]); bfA[r+4] = 0;
            bfB[r] = (short)f2bf(pB[r]); bfB[r+4] = 0;
        }
        #pragma unroll
        for (int dt = 0; dt < 4; ++dt) {
            short8 av;
            av[0]=vv[dt][0]; av[1]=vv[dt][1]; av[2]=vv[dt][2]; av[3]=vv[dt][3];
            av[4]=0; av[5]=0; av[6]=0; av[7]=0;
            oaA[dt] = mfma16(av, bfA, oaA[dt]);
            oaB[dt] = mfma16(av, bfB, oaB[dt]);
        }
    }
    for (int kt = nA; kt < nB; ++kt) {
        const short8 a0 = c0, a1 = c1;
        short4v vv[4];
        #pragma unroll
        for (int dt = 0; dt < 4; ++dt) vv[dt] = vc[dt];
        if (kt + 1 < nB) {
            const unsigned short* np = kptr + (kt + 1) * (16*NDIM);
            c0 = *(const short8*)(np);
            c1 = *(const short8*)(np + 32);
            const unsigned short* vp = vbase + (kt + 1) * 16;
            #pragma unroll
            for (int dt = 0; dt < 4; ++dt) vc[dt] = *(const short4v*)(vp + dt*(16*NSEQ));
        }
        f32x4 sB = {0.f,0.f,0.f,0.f};
        sB = mfma16(a0, qfB0, sB); sB = mfma16(a1, qfB1, sB);
        const int kb = (kt << 4) + (g << 2);
        f32x4 pB;
        #pragma unroll
        for (int r = 0; r < 4; ++r) {
            const float eB = fexp2(sB[r] * CEXPF) * invB;
            pB[r] = (kb + r <= qaB) ? eB : 0.0f;
        }
        __builtin_nontemporal_store(zero4, (f32x4*)(attA + (kt << 4)));
        __builtin_nontemporal_store(pB,    (f32x4*)(attB + (kt << 4)));
        short8 bfB;
        #pragma unroll
        for (int r = 0; r < 4; ++r) { bfB[r] = (short)f2bf(pB[r]); bfB[r+4] = 0; }
        #pragma unroll
        for (int dt = 0; dt < 4; ++dt) {
            short8 av;
            av[0]=vv[dt][0]; av[1]=vv[dt][1]; av[2]=vv[dt][2]; av[3]=vv[dt][3];
            av[4]=0; av[5]=0; av[6]=0; av[7]=0;
            oaB[dt] = mfma16(av, bfB, oaB[dt]);
        }
    }
    for (int kt = nB; kt < 128; ++kt) {
        __builtin_nontemporal_store(zero4, (f32x4*)(attA + (kt << 4)));
        __builtin_nontemporal_store(zero4, (f32x4*)(attB + (kt << 4)));
    }

    float* oAp = outA + ((long)b*NSEQ + qaA) * NNX + h*64 + (g << 2);
    float* oBp = outA + ((long)b*NSEQ + qaB) * NNX + h*64 + (g << 2);
    #pragma unroll
    for (int dt = 0; dt < 4; ++dt) {
        *(f32x4*)(oAp + dt*16) = oaA[dt];
        *(f32x4*)(oBp + dt*16) = oaB[dt];
    }
}

extern "C" void kernel_launch(void* const* d_in, const int* in_sizes, int n_in,
                              void* d_out, int out_size, void* d_ws, size_t ws_size,
                              hipStream_t stream) {
    const float* q  = (const float*)d_in[0];
    const float* k  = (const float*)d_in[1];
    const float* v  = (const float*)d_in[2];
    const float* kr = (const float*)d_in[3];
    const size_t tensor_elems = (size_t)NBH * NSEQ * NDIM;   // 4,194,304
    if (ws_size < 3 * tensor_elems * sizeof(unsigned short)) return;  // need 24 MiB scratch
    unsigned short* Qb  = (unsigned short*)d_ws;
    unsigned short* KKb = Qb + tensor_elems;
    unsigned short* VT  = KKb + tensor_elems;
    float* outA   = (float*)d_out;
    float* outAtt = outA + (size_t)NBATCH * NSEQ * NNX;

    hipLaunchKernelGGL(prep_qk,   dim3(4096), dim3(256), 0, stream, q, k, kr, Qb, KKb);
    hipLaunchKernelGGL(prep_vt,   dim3(1024), dim3(256), 0, stream, v, VT);
    hipLaunchKernelGGL(attn_main, dim3(512),  dim3(256), 0, stream, Qb, KKb, VT, outA, outAtt);
}

// Round 2
// 300.031 us; speedup vs baseline: 1.0229x; 1.0229x over previous
//
#include <hip/hip_runtime.h>

#define NBATCH 2
#define NHEAD  16
#define NSEQ   2048
#define NDIM   64
#define NNX    1024
#define NBH    (NBATCH*NHEAD)
#define CEXPF  0.18033688011112042f   // log2(e)/sqrt(64)

typedef short          short8  __attribute__((ext_vector_type(8)));
typedef short          short4v __attribute__((ext_vector_type(4)));
typedef unsigned short us4     __attribute__((ext_vector_type(4)));
typedef unsigned short us8     __attribute__((ext_vector_type(8)));
typedef float          f32x4   __attribute__((ext_vector_type(4)));

__device__ __forceinline__ unsigned short f2bf(float f) {
    unsigned int u = __builtin_bit_cast(unsigned int, f);
    u += 0x7FFFu + ((u >> 16) & 1u);           // round-to-nearest-even
    return (unsigned short)(u >> 16);
}

__device__ __forceinline__ float fexp2(float x) {
#if __has_builtin(__builtin_amdgcn_exp2f)
    return __builtin_amdgcn_exp2f(x);
#else
    return exp2f(x);
#endif
}

__device__ __forceinline__ f32x4 mfma16(short8 a, short8 b, f32x4 c) {
    return __builtin_amdgcn_mfma_f32_16x16x32_bf16(a, b, c, 0, 0, 0);
}

// ---- prep: Qb = bf16 split-heads query [bh][s][d]; KKb = bf16 (key+key_r) ----
__global__ __launch_bounds__(256) void prep_qk(
        const float* __restrict__ q, const float* __restrict__ k,
        const float* __restrict__ kr,
        unsigned short* __restrict__ Qb, unsigned short* __restrict__ KKb) {
    const long i    = (long)blockIdx.x * 256 + threadIdx.x;   // 0..1048575
    const long flat = i << 2;
    const int dnx = (int)(flat & (NNX - 1));
    const int s   = (int)((flat >> 10) & (NSEQ - 1));
    const int b   = (int)(flat >> 21);
    const int h   = dnx >> 6;
    const int d   = dnx & 63;
    const long o  = ((long)(b*NHEAD + h) * NSEQ + s) * NDIM + d;
    const float4 qv = *(const float4*)(q  + flat);
    const float4 kv = *(const float4*)(k  + flat);
    const float4 rv = *(const float4*)(kr + flat);
    us4 qo, ko;
    qo[0]=f2bf(qv.x); qo[1]=f2bf(qv.y); qo[2]=f2bf(qv.z); qo[3]=f2bf(qv.w);
    ko[0]=f2bf(kv.x+rv.x); ko[1]=f2bf(kv.y+rv.y); ko[2]=f2bf(kv.z+rv.z); ko[3]=f2bf(kv.w+rv.w);
    *(us4*)(Qb  + o) = qo;
    *(us4*)(KKb + o) = ko;
}

// ---- prep: VT = bf16 value transposed per head: [bh][d][s] ----
__global__ __launch_bounds__(256) void prep_vt(const float* __restrict__ v,
        unsigned short* __restrict__ VT) {
    __shared__ unsigned short lds[64][66];
    const int bh = blockIdx.x & (NBH - 1);
    const int st = blockIdx.x >> 5;          // s-tile of 64
    const int b = bh >> 4, h = bh & 15;
    const int t  = threadIdx.x;
    const int sl = t >> 2;
    const int d0 = (t & 3) << 4;
    const float* src = v + ((long)b*NSEQ + st*64 + sl) * NNX + h*64 + d0;
    #pragma unroll
    for (int j = 0; j < 4; ++j) {
        float4 x = *(const float4*)(src + j*4);
        lds[d0 + j*4 + 0][sl] = f2bf(x.x);
        lds[d0 + j*4 + 1][sl] = f2bf(x.y);
        lds[d0 + j*4 + 2][sl] = f2bf(x.z);
        lds[d0 + j*4 + 3][sl] = f2bf(x.w);
    }
    __syncthreads();
    const int d  = t >> 2;
    const int s0 = (t & 3) << 4;
    unsigned short* dst = VT + ((long)bh*NDIM + d)*NSEQ + st*64 + s0;
    us8 o0, o1;
    #pragma unroll
    for (int j = 0; j < 8; ++j) { o0[j] = lds[d][s0+j]; o1[j] = lds[d][s0+8+j]; }
    *(us8*)(dst)     = o0;
    *(us8*)(dst + 8) = o1;
}

// ---- fused attention: one 16-row q-tile per wave; waves w and w+4 of a block
// ---- handle complementary tiles (a, 127-a) so every SIMD's load is uniform.
__global__ __launch_bounds__(512, 4) void attn_main(
        const unsigned short* __restrict__ Qb,
        const unsigned short* __restrict__ KKb,
        const unsigned short* __restrict__ VT,
        float* __restrict__ outA, float* __restrict__ outAtt) {
    const int lane = threadIdx.x & 63;
    const int w    = threadIdx.x >> 6;                 // 0..7
    const int p    = (blockIdx.x << 2) | (w & 3);      // pair id 0..2047
    const int bh   = p & (NBH - 1);
    const int aIdx = p >> 5;                           // 0..63
    const int t    = (w < 4) ? aIdx : (127 - aIdx);    // q-tile 0..127
    const int b = bh >> 4, h = bh & 15;
    const int r16 = lane & 15;
    const int g   = lane >> 4;
    const int qa  = (t << 4) + r16;                    // this lane's q row

    const unsigned short* Qp = Qb  + (long)bh * (NSEQ*NDIM);
    const unsigned short* Kp = KKb + (long)bh * (NSEQ*NDIM);
    const unsigned short* Vp = VT  + (long)bh * (NDIM*NSEQ);

    const short8 qf0 = *(const short8*)(Qp + qa*NDIM + g*8);
    const short8 qf1 = *(const short8*)(Qp + qa*NDIM + g*8 + 32);
    const unsigned short* kptr = Kp + r16*NDIM + g*8;

    // ---------------- pass 1: row sums of exp (max-free; |w| bounded ~10) ----------------
    float ls[4] = {0.f,0.f,0.f,0.f};
    short8 c0 = *(const short8*)(kptr);
    short8 c1 = *(const short8*)(kptr + 32);
    #pragma unroll 2
    for (int kt = 0; kt < t; ++kt) {               // tiles 0..t-1: never masked
        const short8 a0 = c0, a1 = c1;
        const unsigned short* np = kptr + (kt + 1) * (16*NDIM);
        c0 = *(const short8*)(np);
        c1 = *(const short8*)(np + 32);
        f32x4 s = {0.f,0.f,0.f,0.f};
        s = mfma16(a0, qf0, s);
        s = mfma16(a1, qf1, s);
        #pragma unroll
        for (int r = 0; r < 4; ++r) ls[r] += fexp2(s[r] * CEXPF);
    }
    {   // diagonal tile t: mask col - row: g*4+r <= r16
        f32x4 s = {0.f,0.f,0.f,0.f};
        s = mfma16(c0, qf0, s);
        s = mfma16(c1, qf1, s);
        #pragma unroll
        for (int r = 0; r < 4; ++r) {
            const float e = fexp2(s[r] * CEXPF);
            ls[r] += (g*4 + r <= r16) ? e : 0.0f;
        }
    }
    float l = ls[0]+ls[1]+ls[2]+ls[3];
    l += __shfl_xor(l, 16, 64);
    l += __shfl_xor(l, 32, 64);
    const float inv = 1.0f / l;

    // ---------------- pass 2: recompute, write att (NT, kt-paired), accumulate PV ----------------
    const f32x4 zero4 = {0.f,0.f,0.f,0.f};
    f32x4 oa[4];
    #pragma unroll
    for (int dt = 0; dt < 4; ++dt) oa[dt] = zero4;

    float* att = outAtt + ((long)bh*NSEQ + qa) * NSEQ + (g << 2);
    const unsigned short* vbase = Vp + r16*NSEQ + (g << 2);

    c0 = *(const short8*)(kptr);
    c1 = *(const short8*)(kptr + 32);
    const unsigned short* np1 = kptr + ((t > 0) ? 1 : 0) * (16*NDIM);
    short8 d0 = *(const short8*)(np1);
    short8 d1 = *(const short8*)(np1 + 32);

    int kt = 0;
    for (; kt + 2 <= t; kt += 2) {                 // pairs of unmasked tiles
        const short8 a00 = c0, a01 = c1, a10 = d0, a11 = d1;
        const int i2 = (kt + 2 < t) ? kt + 2 : t;
        const int i3 = (kt + 3 < t) ? kt + 3 : t;
        const unsigned short* np2 = kptr + i2 * (16*NDIM);
        const unsigned short* np3 = kptr + i3 * (16*NDIM);
        c0 = *(const short8*)(np2); c1 = *(const short8*)(np2 + 32);
        d0 = *(const short8*)(np3); d1 = *(const short8*)(np3 + 32);

        short4v v0[4], v1[4];
        const unsigned short* vp0 = vbase + kt * 16;
        #pragma unroll
        for (int dt = 0; dt < 4; ++dt) {
            v0[dt] = *(const short4v*)(vp0 + dt*(16*NSEQ));
            v1[dt] = *(const short4v*)(vp0 + 16 + dt*(16*NSEQ));
        }

        f32x4 s0 = zero4, s1 = zero4;
        s0 = mfma16(a00, qf0, s0); s0 = mfma16(a01, qf1, s0);
        s1 = mfma16(a10, qf0, s1); s1 = mfma16(a11, qf1, s1);
        f32x4 p0, p1;
        #pragma unroll
        for (int r = 0; r < 4; ++r) {
            p0[r] = fexp2(s0[r] * CEXPF) * inv;
            p1[r] = fexp2(s1[r] * CEXPF) * inv;
        }
        // adjacent 64B halves of each 128B att line, issued back-to-back
        __builtin_nontemporal_store(p0, (f32x4*)(att + (kt << 4)));
        __builtin_nontemporal_store(p1, (f32x4*)(att + (kt << 4) + 16));

        short8 b0, b1;
        #pragma unroll
        for (int r = 0; r < 4; ++r) {
            b0[r] = (short)f2bf(p0[r]); b0[r+4] = 0;
            b1[r] = (short)f2bf(p1[r]); b1[r+4] = 0;
        }
        #pragma unroll
        for (int dt = 0; dt < 4; ++dt) {
            short8 av0, av1;
            av0[0]=v0[dt][0]; av0[1]=v0[dt][1]; av0[2]=v0[dt][2]; av0[3]=v0[dt][3];
            av0[4]=0; av0[5]=0; av0[6]=0; av0[7]=0;
            av1[0]=v1[dt][0]; av1[1]=v1[dt][1]; av1[2]=v1[dt][2]; av1[3]=v1[dt][3];
            av1[4]=0; av1[5]=0; av1[6]=0; av1[7]=0;
            oa[dt] = mfma16(av0, b0, oa[dt]);
            oa[dt] = mfma16(av1, b1, oa[dt]);
        }
    }
    if (kt < t) {   // one leftover unmasked tile (t odd), data in c0/c1
        short4v v0[4];
        const unsigned short* vp0 = vbase + kt * 16;
        #pragma unroll
        for (int dt = 0; dt < 4; ++dt) v0[dt] = *(const short4v*)(vp0 + dt*(16*NSEQ));
        f32x4 s0 = zero4;
        s0 = mfma16(c0, qf0, s0); s0 = mfma16(c1, qf1, s0);
        f32x4 p0;
        #pragma unroll
        for (int r = 0; r < 4; ++r) p0[r] = fexp2(s0[r] * CEXPF) * inv;
        __builtin_nontemporal_store(p0, (f32x4*)(att + (kt << 4)));
        short8 b0;
        #pragma unroll
        for (int r = 0; r < 4; ++r) { b0[r] = (short)f2bf(p0[r]); b0[r+4] = 0; }
        #pragma unroll
        for (int dt = 0; dt < 4; ++dt) {
            short8 av0;
            av0[0]=v0[dt][0]; av0[1]=v0[dt][1]; av0[2]=v0[dt][2]; av0[3]=v0[dt][3];
            av0[4]=0; av0[5]=0; av0[6]=0; av0[7]=0;
            oa[dt] = mfma16(av0, b0, oa[dt]);
        }
        c0 = d0; c1 = d1;
        ++kt;
    }
    {   // diagonal tile t (data in c0/c1), masked
        short4v v0[4];
        const unsigned short* vp0 = vbase + t * 16;
        #pragma unroll
        for (int dt = 0; dt < 4; ++dt) v0[dt] = *(const short4v*)(vp0 + dt*(16*NSEQ));
        f32x4 s0 = zero4;
        s0 = mfma16(c0, qf0, s0); s0 = mfma16(c1, qf1, s0);
        f32x4 p0;
        #pragma unroll
        for (int r = 0; r < 4; ++r) {
            const float e = fexp2(s0[r] * CEXPF) * inv;
            p0[r] = (g*4 + r <= r16) ? e : 0.0f;
        }
        __builtin_nontemporal_store(p0, (f32x4*)(att + (t << 4)));
        short8 b0;
        #pragma unroll
        for (int r = 0; r < 4; ++r) { b0[r] = (short)f2bf(p0[r]); b0[r+4] = 0; }
        #pragma unroll
        for (int dt = 0; dt < 4; ++dt) {
            short8 av0;
            av0[0]=v0[dt][0]; av0[1]=v0[dt][1]; av0[2]=v0[dt][2]; av0[3]=v0[dt][3];
            av0[4]=0; av0[5]=0; av0[6]=0; av0[7]=0;
            oa[dt] = mfma16(av0, b0, oa[dt]);
        }
    }
    // zero the future (cols > diagonal tile): 4 adjacent stores = 256B/row bursts
    #pragma unroll 4
    for (int z = t + 1; z < 128; ++z)
        __builtin_nontemporal_store(zero4, (f32x4*)(att + (z << 4)));

    float* oA = outA + ((long)b*NSEQ + qa) * NNX + h*64 + (g << 2);
    #pragma unroll
    for (int dt = 0; dt < 4; ++dt)
        *(f32x4*)(oA + dt*16) = oa[dt];
}

extern "C" void kernel_launch(void* const* d_in, const int* in_sizes, int n_in,
                              void* d_out, int out_size, void* d_ws, size_t ws_size,
                              hipStream_t stream) {
    const float* q  = (const float*)d_in[0];
    const float* k  = (const float*)d_in[1];
    const float* v  = (const float*)d_in[2];
    const float* kr = (const float*)d_in[3];
    const size_t tensor_elems = (size_t)NBH * NSEQ * NDIM;   // 4,194,304
    if (ws_size < 3 * tensor_elems * sizeof(unsigned short)) return;  // need 24 MiB scratch
    unsigned short* Qb  = (unsigned short*)d_ws;
    unsigned short* KKb = Qb + tensor_elems;
    unsigned short* VT  = KKb + tensor_elems;
    float* outA   = (float*)d_out;
    float* outAtt = outA + (size_t)NBATCH * NSEQ * NNX;

    hipLaunchKernelGGL(prep_qk,   dim3(4096), dim3(256), 0, stream, q, k, kr, Qb, KKb);
    hipLaunchKernelGGL(prep_vt,   dim3(1024), dim3(256), 0, stream, v, VT);
    hipLaunchKernelGGL(attn_main, dim3(512),  dim3(512), 0, stream, Qb, KKb, VT, outA, outAtt);
}